// Round 6
// baseline (248.035 us; speedup 1.0000x reference)
//
#include <hip/hip_runtime.h>
#include <math.h>

// Problem constants (from reference): N=65536 rows, D=512 features, K=5 centroids.
#define LFR_N 65536
#define LFR_D 512
#define LFR_K 5
#define RPW   16                         // rows per wave (one per lane&15)
#define WPB   4                          // waves per block (256 threads)
#define NCH   (LFR_D / 64)               // 8 chunks of 64 d
#define BLOCKS (LFR_N / (RPW * WPB))     // 1024 blocks = 4/CU, all resident

// R6: INVERTED PARALLELISM (lane-per-row, LDS-staged).
// R0-R5: five structures (VALU -50%, shuffle -60%, prefetch streaming, 1KB
// coalescing, read/write stream split) ALL land 81-88us = 3.1 TB/s combined
// traffic, half the float4-copy ceiling. Shared invariant: 64-lane-per-row
// reduce/broadcast structure - phase-locked waves, 2-8 loads in flight,
// long dependent shuffle chains. This kernel inverts it: lane owns rows,
// x staged via LDS (global->reg->swizzled tile->reg), dist accumulates in
// registers with ZERO shuffles in the hot loop; 2-step shfl reduce + scalar
// softmax per row at the end; rec generated and staged back through the same
// tile for 1KB coalesced stores. Waves desync; 4 stage-loads always in
// flight per wave (16 waves/CU -> ~512 lines outstanding/CU, need ~144).
// Cross-lane LDS dependences are wave-internal: explicit lgkmcnt(0) +
// sched_barrier instead of __syncthreads (no block phase-lock). f4-XOR
// swizzle (col4 ^ row) keeps ds_read/ds_write at the b128 8-way floor.

#define LGKM0() do { asm volatile("s_waitcnt lgkmcnt(0)" ::: "memory"); \
                     __builtin_amdgcn_sched_barrier(0); } while (0)

__global__ __launch_bounds__(256) void lfr_kernel(
    const float* __restrict__ x,        // (N, D)
    const float* __restrict__ alpha,    // (D,)
    const float* __restrict__ w,        // (K, 1)
    const float* __restrict__ cent,     // (K, D)
    float* __restrict__ out_map,        // (N, K)
    float* __restrict__ out_rec,        // (N, D)
    float* __restrict__ out_pred)       // (N,)
{
    __shared__ float  sc[LFR_K][LFR_D];  // 10 KB centroids (block-shared)
    __shared__ float  sa[LFR_D];         //  2 KB alpha
    __shared__ float4 sx[WPB][16][16];   // 16 KB per-wave x/rec tile, f4-XOR swizzled

    const int tid  = threadIdx.x;
    const int lane = tid & 63;
    const int wib  = tid >> 6;
    const int rr   = lane & 15;          // row-in-tile this lane owns
    const int qq   = lane >> 4;          // d-quarter within each 64-chunk

    // ---- cooperative stage of cent+alpha (once per block) ----
    {
        const float4* csrc = (const float4*)cent;         // 640 float4
        float4* cdst = (float4*)&sc[0][0];
        #pragma unroll
        for (int i = 0; i < 3; ++i) {
            int idx = tid + i * 256;
            if (idx < (LFR_K * LFR_D) / 4) cdst[idx] = csrc[idx];
        }
        if (tid < LFR_D / 4) ((float4*)sa)[tid] = ((const float4*)alpha)[tid];
    }
    float sigw[LFR_K];
    #pragma unroll
    for (int k = 0; k < LFR_K; ++k) sigw[k] = 1.0f / (1.0f + __expf(-w[k]));
    __syncthreads();   // the ONLY block barrier

    const int r0 = (blockIdx.x * WPB + wib) * RPW;   // this wave's 16 rows

    // ---- pass 1: stream x chunks, accumulate dist in registers ----
    // stage-load layout: inst i covers rows i*4+qq, 256B full-line segments.
    float4 pf[4];
    #pragma unroll
    for (int i = 0; i < 4; ++i)
        pf[i] = *(const float4*)(x + (size_t)(r0 + i*4 + qq) * LFR_D + rr*4);

    float dacc[LFR_K] = {0.f, 0.f, 0.f, 0.f, 0.f};

    #pragma unroll
    for (int ch = 0; ch < NCH; ++ch) {
        if (ch) LGKM0();                 // WAR: prior chunk's tile reads retired
        #pragma unroll
        for (int i = 0; i < 4; ++i) {
            const int row = i*4 + qq;
            sx[wib][row][rr ^ row] = pf[i];      // vmcnt wait auto-inserted
        }
        if (ch + 1 < NCH) {              // keep 4 x 1KB loads in flight
            #pragma unroll
            for (int i = 0; i < 4; ++i)
                pf[i] = *(const float4*)(x + (size_t)(r0 + i*4 + qq) * LFR_D
                                           + (ch + 1) * 64 + rr*4);
        }
        LGKM0();                         // RAW: tile writes visible wave-wide
        #pragma unroll
        for (int j4 = 0; j4 < 4; ++j4) {
            const int col4 = qq*4 + j4;
            float4 xv = sx[wib][rr][col4 ^ rr];
            float4 av = ((const float4*)&sa[ch * 64])[col4];   // broadcast read
            #pragma unroll
            for (int k = 0; k < LFR_K; ++k) {
                float4 cv = ((const float4*)&sc[k][ch * 64])[col4];
                float d0 = xv.x - cv.x, d1 = xv.y - cv.y;
                float d2 = xv.z - cv.z, d3 = xv.w - cv.w;
                dacc[k] = fmaf(av.x * d0, d0, dacc[k]);
                dacc[k] = fmaf(av.y * d1, d1, dacc[k]);
                dacc[k] = fmaf(av.z * d2, d2, dacc[k]);
                dacc[k] = fmaf(av.w * d3, d3, dacc[k]);
            }
        }
    }

    // ---- reduce the 4 d-quarters of each row (2 shuffle steps, once) ----
    #pragma unroll
    for (int k = 0; k < LFR_K; ++k) {
        dacc[k] += __shfl_xor(dacc[k], 16);
        dacc[k] += __shfl_xor(dacc[k], 32);
    }

    // ---- softmax per lane (every lane has its row's full dist) ----
    float e[LFR_K];
    float mx = dacc[0];
    #pragma unroll
    for (int k = 1; k < LFR_K; ++k) mx = fmaxf(mx, dacc[k]);
    float sum = 0.f;
    #pragma unroll
    for (int k = 0; k < LFR_K; ++k) { e[k] = __expf(dacc[k] - mx); sum += e[k]; }
    float inv = 1.0f / sum;
    #pragma unroll
    for (int k = 0; k < LFR_K; ++k) e[k] *= inv;

    // ---- map + pred: quarter-0 lane of each row writes (16 rows, 320B run) ----
    if (qq == 0) {
        float* mp = out_map + (size_t)(r0 + rr) * LFR_K;
        #pragma unroll
        for (int k = 0; k < LFR_K; ++k) mp[k] = e[k];
        float pr = e[0] * sigw[0];
        #pragma unroll
        for (int k = 1; k < LFR_K; ++k) pr = fmaf(e[k], sigw[k], pr);
        out_pred[r0 + rr] = pr;
    }

    // ---- pass 2: generate rec, stage through tile, 1KB coalesced stores ----
    #pragma unroll
    for (int ch = 0; ch < NCH; ++ch) {
        LGKM0();                         // WAR: prior chunk's store-reads retired
        #pragma unroll
        for (int j4 = 0; j4 < 4; ++j4) {
            const int col4 = qq*4 + j4;
            float4 c0 = ((const float4*)&sc[0][ch * 64])[col4];
            float4 rv;
            rv.x = e[0] * c0.x; rv.y = e[0] * c0.y;
            rv.z = e[0] * c0.z; rv.w = e[0] * c0.w;
            #pragma unroll
            for (int k = 1; k < LFR_K; ++k) {
                float4 cv = ((const float4*)&sc[k][ch * 64])[col4];
                rv.x = fmaf(e[k], cv.x, rv.x);
                rv.y = fmaf(e[k], cv.y, rv.y);
                rv.z = fmaf(e[k], cv.z, rv.z);
                rv.w = fmaf(e[k], cv.w, rv.w);
            }
            sx[wib][rr][col4 ^ rr] = rv;
        }
        LGKM0();                         // RAW: rec tile visible wave-wide
        #pragma unroll
        for (int i = 0; i < 4; ++i) {
            const int row = i*4 + qq;
            float4 v = sx[wib][row][rr ^ row];
            *(float4*)(out_rec + (size_t)(r0 + row) * LFR_D + ch * 64 + rr*4) = v;
        }
    }
}

extern "C" void kernel_launch(void* const* d_in, const int* in_sizes, int n_in,
                              void* d_out, int out_size, void* d_ws, size_t ws_size,
                              hipStream_t stream) {
    const float* x     = (const float*)d_in[0];   // (N, D)
    // d_in[1] = is_protected — unused by the reference computation
    const float* alpha = (const float*)d_in[2];   // (D,)
    const float* w     = (const float*)d_in[3];   // (K, 1)
    const float* cent  = (const float*)d_in[4];   // (K, D)

    float* out   = (float*)d_out;
    float* o_map = out;                                         // N*K
    float* o_rec = out + (size_t)LFR_N * LFR_K;                 // N*D
    float* o_prd = out + (size_t)LFR_N * LFR_K + (size_t)LFR_N * LFR_D;  // N

    // 1024 blocks x 256 threads: 4 blocks/CU all resident, wave = 16 rows,
    // lane-per-row consumption, zero block barriers in the hot loop.
    dim3 grid(BLOCKS), block(256);
    lfr_kernel<<<grid, block, 0, stream>>>(x, alpha, w, cent, o_map, o_rec, o_prd);
}